// Round 2
// baseline (535.784 us; speedup 1.0000x reference)
//
#include <hip/hip_runtime.h>
#include <math.h>
#include <stdio.h>

#define DIMC 1024
#define SEQ 4096
#define BATCH 4
#define NH 16
#define HD 64
#define MTOT (BATCH * SEQ)      // 16384 rows
#define NSPLIT 16
#define EPS 1e-6f

typedef __bf16 bf16x8 __attribute__((ext_vector_type(8)));
typedef __bf16 bf16x4 __attribute__((ext_vector_type(4)));
typedef float  f32x4  __attribute__((ext_vector_type(4)));

__device__ __forceinline__ float phi_f(float x) {
    // elu(x)+1 : x>0 -> x+1 ; x<=0 -> exp(x)
    return x > 0.0f ? x + 1.0f : __expf(x);
}

// ---------------------------------------------------------------------------
// fp32 -> bf16 conversion, 4 elems/thread (n must be multiple of 4)
// ---------------------------------------------------------------------------
__global__ __launch_bounds__(256) void cvt_bf16(
    const float* __restrict__ in, __bf16* __restrict__ out, int n)
{
    const int i = (blockIdx.x * 256 + threadIdx.x) * 4;
    if (i < n) {
        float4 v = *(const float4*)(in + i);
        bf16x4 o = { (__bf16)v.x, (__bf16)v.y, (__bf16)v.z, (__bf16)v.w };
        *(bf16x4*)(out + i) = o;
    }
}

__global__ __launch_bounds__(256) void zero_f32(float* __restrict__ p, int n)
{
    const int i = blockIdx.x * 256 + threadIdx.x;
    if (i < n) p[i] = 0.0f;
}

// ---------------------------------------------------------------------------
// Y[M,N] = X[M,K] @ W[N,K]^T + bias. bf16 inputs, fp32 MFMA accumulate.
// 128x128 block tile, BK=32, 4 waves, each wave 4x4 grid of 16x16x32 MFMA.
// OUT_BF16: write bf16 (intermediates) vs fp32 (final). DO_PHI: elu+1.
// ---------------------------------------------------------------------------
template<int OUT_BF16, int DO_PHI>
__global__ __launch_bounds__(256) void gemm_bf16(
    const __bf16* __restrict__ X, const __bf16* __restrict__ W,
    const float* __restrict__ bias, void* __restrict__ Yv,
    int N, int K)
{
    __shared__ __attribute__((aligned(16))) __bf16 As[128 * 32]; // [m][k]
    __shared__ __attribute__((aligned(16))) __bf16 Bs[128 * 32]; // [n][k]
    const int tid = threadIdx.x;
    const int m0 = blockIdx.y * 128, n0 = blockIdx.x * 128;
    const int wave = tid >> 6, lane = tid & 63;
    const int wm = (wave >> 1) * 64, wn = (wave & 1) * 64;

    f32x4 acc[4][4] = {};

    for (int k0 = 0; k0 < K; k0 += 32) {
        // stage: each thread carries 2 chunks of 8 bf16 for A and B
        bf16x8 av[2], bv[2];
        #pragma unroll
        for (int c = 0; c < 2; ++c) {
            const int chunk = tid + 256 * c;            // 0..511
            const int r = chunk >> 2, kk = (chunk & 3) * 8;
            av[c] = *(const bf16x8*)(X + (size_t)(m0 + r) * K + k0 + kk);
            bv[c] = *(const bf16x8*)(W + (size_t)(n0 + r) * K + k0 + kk);
        }
        __syncthreads();   // previous iteration's ds_reads complete
        #pragma unroll
        for (int c = 0; c < 2; ++c) {
            const int chunk = tid + 256 * c;
            const int r = chunk >> 2, kk = (chunk & 3) * 8;
            *(bf16x8*)(As + r * 32 + kk) = av[c];
            *(bf16x8*)(Bs + r * 32 + kk) = bv[c];
        }
        __syncthreads();

        // fragments: A/B operand layout [row=lane&15][k=(lane>>4)*8 + j]
        const int fr = lane & 15, fk = (lane >> 4) * 8;
        bf16x8 af[4], bfr[4];
        #pragma unroll
        for (int i = 0; i < 4; ++i)
            af[i] = *(const bf16x8*)(As + (wm + i * 16 + fr) * 32 + fk);
        #pragma unroll
        for (int j = 0; j < 4; ++j)
            bfr[j] = *(const bf16x8*)(Bs + (wn + j * 16 + fr) * 32 + fk);
        #pragma unroll
        for (int i = 0; i < 4; ++i)
            #pragma unroll
            for (int j = 0; j < 4; ++j)
                acc[i][j] = __builtin_amdgcn_mfma_f32_16x16x32_bf16(
                    af[i], bfr[j], acc[i][j], 0, 0, 0);
    }

    // epilogue: C/D layout col=lane&15, row=(lane>>4)*4+reg
    const int col_l = lane & 15, quad = lane >> 4;
    #pragma unroll
    for (int j = 0; j < 4; ++j) {
        const int gcol = n0 + wn + j * 16 + col_l;
        const float bb = bias[gcol];
        #pragma unroll
        for (int i = 0; i < 4; ++i) {
            #pragma unroll
            for (int r = 0; r < 4; ++r) {
                const int grow = m0 + wm + i * 16 + quad * 4 + r;
                float v = acc[i][j][r] + bb;
                if (DO_PHI) v = phi_f(v);
                if (OUT_BF16)
                    ((__bf16*)Yv)[(size_t)grow * N + gcol] = (__bf16)v;
                else
                    ((float*)Yv)[(size_t)grow * N + gcol] = v;
            }
        }
    }
}

// ---------------------------------------------------------------------------
// Per (b,h): KV[d][e] = sum_n K[n,d]*V[n,e] ; Z[d] = sum_n K[n,d]
// Split over tokens (NSPLIT partials), fp32 atomics; KV/Z pre-zeroed.
// ---------------------------------------------------------------------------
__global__ __launch_bounds__(256) void kv_z_kernel(
    const __bf16* __restrict__ Kb, const __bf16* __restrict__ Vb,
    float* __restrict__ KV, float* __restrict__ Z)
{
    __shared__ __align__(16) float Ks[16][64];
    __shared__ __align__(16) float Vs[16][64];
    const int tid = threadIdx.x;
    const int bh = blockIdx.x;            // 0..63
    const int b = bh >> 4, h = bh & 15;
    const int n0 = blockIdx.y * (SEQ / NSPLIT);
    const __bf16* Kp = Kb + ((size_t)b * SEQ) * DIMC + h * HD;
    const __bf16* Vp = Vb + ((size_t)b * SEQ) * DIMC + h * HD;
    const int tx = tid & 15, ty = tid >> 4;
    const int lrow = tid >> 4;            // token within chunk (0..15)
    const int lcol = (tid & 15) * 4;      // col within head slice

    float acc[4][4] = {};
    float zacc = 0.0f;
    for (int nc = 0; nc < SEQ / NSPLIT; nc += 16) {
        const int n = n0 + nc + lrow;
        bf16x4 k4 = *(const bf16x4*)(Kp + (size_t)n * DIMC + lcol);
        bf16x4 v4 = *(const bf16x4*)(Vp + (size_t)n * DIMC + lcol);
        #pragma unroll
        for (int q = 0; q < 4; ++q) {
            Ks[lrow][lcol + q] = (float)k4[q];
            Vs[lrow][lcol + q] = (float)v4[q];
        }
        __syncthreads();
        #pragma unroll
        for (int nn = 0; nn < 16; ++nn) {
            float a[4], bb[4];
            #pragma unroll
            for (int i = 0; i < 4; ++i) a[i] = Ks[nn][ty * 4 + i];
            #pragma unroll
            for (int j = 0; j < 4; ++j) bb[j] = Vs[nn][tx * 4 + j];
            #pragma unroll
            for (int i = 0; i < 4; ++i)
                #pragma unroll
                for (int j = 0; j < 4; ++j)
                    acc[i][j] = fmaf(a[i], bb[j], acc[i][j]);
        }
        if (tid < 64) {
            #pragma unroll
            for (int nn = 0; nn < 16; ++nn) zacc += Ks[nn][tid];
        }
        __syncthreads();
    }

    float* KVp = KV + (size_t)bh * HD * HD;
    #pragma unroll
    for (int i = 0; i < 4; ++i)
        #pragma unroll
        for (int j = 0; j < 4; ++j)
            atomicAdd(&KVp[(ty * 4 + i) * HD + (tx * 4 + j)], acc[i][j]);
    if (tid < 64) atomicAdd(&Z[bh * HD + tid], zacc);
}

// ---------------------------------------------------------------------------
// Per (b,h, 32-token chunk): out[n,e] = (sum_d Q[n,d]*KV[d,e]) / (Q[n]·Z + eps)
// Q bf16 in, A bf16 out.
// ---------------------------------------------------------------------------
__global__ __launch_bounds__(256) void attn_apply(
    const __bf16* __restrict__ Qb, const float* __restrict__ KV,
    const float* __restrict__ Z, __bf16* __restrict__ Ab)
{
    __shared__ __align__(16) float KVs[64][64];
    __shared__ __align__(16) float Qs[32][64];
    __shared__ float Zs[64];
    __shared__ float rnorm[32];
    const int tid = threadIdx.x;
    const int bh = blockIdx.y;
    const int b = bh >> 4, h = bh & 15;
    const int n0 = blockIdx.x * 32;

    const float* KVp = KV + (size_t)bh * HD * HD;
    #pragma unroll
    for (int r = 0; r < 4; ++r) {
        const int idx = (r * 256 + tid) * 4;
        *(float4*)&((float*)KVs)[idx] = *(const float4*)(KVp + idx);
    }
    const __bf16* Qp = Qb + ((size_t)(b * SEQ + n0)) * DIMC + h * HD;
    #pragma unroll
    for (int r = 0; r < 2; ++r) {
        const int t = r * 256 + tid;
        const int tok = t >> 4, col = (t & 15) * 4;
        bf16x4 q4 = *(const bf16x4*)(Qp + (size_t)tok * DIMC + col);
        #pragma unroll
        for (int q = 0; q < 4; ++q) Qs[tok][col + q] = (float)q4[q];
    }
    if (tid < 64) Zs[tid] = Z[bh * HD + tid];
    __syncthreads();

    if (tid < 32) {
        float s = 0.0f;
        #pragma unroll
        for (int d = 0; d < 64; ++d) s += Qs[tid][d] * Zs[d];
        rnorm[tid] = 1.0f / (s + EPS);
    }
    __syncthreads();

    const int trow = tid >> 3;          // token 0..31
    const int e0 = (tid & 7) * 8;       // 8 outputs per thread
    float out[8] = {};
    #pragma unroll
    for (int d = 0; d < 64; ++d) {
        const float q = Qs[trow][d];
        #pragma unroll
        for (int j = 0; j < 8; ++j) out[j] = fmaf(q, KVs[d][e0 + j], out[j]);
    }
    const float rn = rnorm[trow];
    __bf16* Op = Ab + ((size_t)(b * SEQ + n0 + trow)) * DIMC + h * HD + e0;
    bf16x8 o;
    #pragma unroll
    for (int j = 0; j < 8; ++j) o[j] = (__bf16)(out[j] * rn);
    *(bf16x8*)Op = o;
}

extern "C" void kernel_launch(void* const* d_in, const int* in_sizes, int n_in,
                              void* d_out, int out_size, void* d_ws, size_t ws_size,
                              hipStream_t stream) {
    const float* x  = (const float*)d_in[0];
    const float* Wq = (const float*)d_in[1];
    const float* bq = (const float*)d_in[2];
    const float* Wk = (const float*)d_in[3];
    const float* bk = (const float*)d_in[4];
    const float* Wv = (const float*)d_in[5];
    const float* bv = (const float*)d_in[6];
    const float* Wo = (const float*)d_in[7];
    const float* bo = (const float*)d_in[8];
    float* out = (float*)d_out;

    fprintf(stderr, "[kernel_launch] ws_size=%zu bytes\n", ws_size);

    const size_t big = (size_t)MTOT * DIMC;     // 16,777,216 elems
    const size_t wsz = (size_t)DIMC * DIMC;     // 1,048,576 elems
    __bf16* ws  = (__bf16*)d_ws;
    __bf16* xb  = ws;                            // 33.5 MB
    __bf16* Wqb = xb + big;
    __bf16* Wkb = Wqb + wsz;
    __bf16* Wvb = Wkb + wsz;
    __bf16* Wob = Wvb + wsz;                     // +8.4 MB
    __bf16* Qb  = Wob + wsz;
    __bf16* Kb  = Qb + big;
    __bf16* Vb  = Kb + big;                      // +100.6 MB
    __bf16* Ab  = xb;                            // alias: x dead after V gemm
    float*  KV  = (float*)(Vb + big);            // 64*64*64 fp32
    float*  Z   = KV + BATCH * NH * HD * HD;     // 64*64 fp32
    // total: ~142.6 MB bf16 + 1.05 MB fp32

    // convert inputs to bf16
    cvt_bf16<<<dim3(big / 1024), 256, 0, stream>>>(x, xb, (int)big);
    cvt_bf16<<<dim3(wsz / 1024), 256, 0, stream>>>(Wq, Wqb, (int)wsz);
    cvt_bf16<<<dim3(wsz / 1024), 256, 0, stream>>>(Wk, Wkb, (int)wsz);
    cvt_bf16<<<dim3(wsz / 1024), 256, 0, stream>>>(Wv, Wvb, (int)wsz);
    cvt_bf16<<<dim3(wsz / 1024), 256, 0, stream>>>(Wo, Wob, (int)wsz);

    const int nz = BATCH * NH * HD * HD + BATCH * NH * HD;
    zero_f32<<<dim3((nz + 255) / 256), 256, 0, stream>>>(KV, nz);

    dim3 gg(DIMC / 128, MTOT / 128);   // (8, 128)
    gemm_bf16<1, 1><<<gg, 256, 0, stream>>>(xb, Wqb, bq, Qb, DIMC, DIMC);
    gemm_bf16<1, 1><<<gg, 256, 0, stream>>>(xb, Wkb, bk, Kb, DIMC, DIMC);
    gemm_bf16<1, 0><<<gg, 256, 0, stream>>>(xb, Wvb, bv, Vb, DIMC, DIMC);

    kv_z_kernel<<<dim3(BATCH * NH, NSPLIT), 256, 0, stream>>>(Kb, Vb, KV, Z);
    attn_apply<<<dim3(SEQ / 32, BATCH * NH), 256, 0, stream>>>(Qb, KV, Z, Ab);

    gemm_bf16<0, 0><<<gg, 256, 0, stream>>>(Ab, Wob, bo, out, DIMC, DIMC);
}

// Round 3
// 463.313 us; speedup vs baseline: 1.1564x; 1.1564x over previous
//
#include <hip/hip_runtime.h>
#include <math.h>

#define DIMC 1024
#define SEQ 4096
#define BATCH 4
#define NH 16
#define HD 64
#define MTOT (BATCH * SEQ)      // 16384 rows
#define NSPLIT 8
#define PELEMS (64 * 64 * 64 + 64 * 64)   // KV partial + Z partial per split
#define EPS 1e-6f

typedef __bf16 bf16x8 __attribute__((ext_vector_type(8)));
typedef __bf16 bf16x4 __attribute__((ext_vector_type(4)));
typedef __bf16 bf16x2 __attribute__((ext_vector_type(2)));
typedef float  f32x4  __attribute__((ext_vector_type(4)));

__device__ __forceinline__ float phi_f(float x) {
    return x > 0.0f ? x + 1.0f : __expf(x);   // elu(x)+1
}

// ---------------------------------------------------------------------------
// fp32 -> bf16 conversion, 4 elems/thread
// ---------------------------------------------------------------------------
__global__ __launch_bounds__(256) void cvt_bf16(
    const float* __restrict__ in, __bf16* __restrict__ out, int n)
{
    const int i = (blockIdx.x * 256 + threadIdx.x) * 4;
    if (i < n) {
        float4 v = *(const float4*)(in + i);
        bf16x4 o = { (__bf16)v.x, (__bf16)v.y, (__bf16)v.z, (__bf16)v.w };
        *(bf16x4*)(out + i) = o;
    }
}

// 4 weight matrices in one dispatch (blockIdx.y picks the matrix)
__global__ __launch_bounds__(256) void cvt_bf16_w4(
    const float* __restrict__ a, const float* __restrict__ b,
    const float* __restrict__ c, const float* __restrict__ d,
    __bf16* __restrict__ oa, __bf16* __restrict__ ob,
    __bf16* __restrict__ oc, __bf16* __restrict__ od, int n)
{
    const float* src; __bf16* dst;
    switch (blockIdx.y) {
        case 0: src = a; dst = oa; break;
        case 1: src = b; dst = ob; break;
        case 2: src = c; dst = oc; break;
        default: src = d; dst = od; break;
    }
    const int i = (blockIdx.x * 256 + threadIdx.x) * 4;
    if (i < n) {
        float4 v = *(const float4*)(src + i);
        bf16x4 o = { (__bf16)v.x, (__bf16)v.y, (__bf16)v.z, (__bf16)v.w };
        *(bf16x4*)(dst + i) = o;
    }
}

// ---------------------------------------------------------------------------
// Y[M,N] = X[M,K] @ W[N,K]^T + bias. m97 structure: global_load_lds width=16
// staging into unpadded [128][32] bf16 tiles, 2-barrier K-loop, 4 waves with
// 4x4 grids of 16x16x32 MFMA.
// ---------------------------------------------------------------------------
template<int OUT_BF16, int DO_PHI>
__global__ __launch_bounds__(256) void gemm_bf16(
    const __bf16* __restrict__ X, const __bf16* __restrict__ W,
    const float* __restrict__ bias, void* __restrict__ Yv,
    int N, int K)
{
    __shared__ __attribute__((aligned(16))) __bf16 As[128 * 32]; // [m][k]
    __shared__ __attribute__((aligned(16))) __bf16 Bs[128 * 32]; // [n][k]
    const int tid = threadIdx.x;
    const int m0 = blockIdx.y * 128, n0 = blockIdx.x * 128;
    const int wave = tid >> 6, lane = tid & 63;
    const int wm = (wave >> 1) * 64, wn = (wave & 1) * 64;
    const int srow = lane >> 2, scol = (lane & 3) * 8;  // staging lane map
    const int fr = lane & 15, fk = (lane >> 4) * 8;     // fragment lane map

    f32x4 acc[4][4] = {};

    for (int k0 = 0; k0 < K; k0 += 32) {
        __syncthreads();   // previous tile's ds_reads complete
        #pragma unroll
        for (int g = 0; g < 2; ++g) {
            const int r0 = wave * 16 + g * 64;   // 16-row group per call
            __builtin_amdgcn_global_load_lds(
                (const __attribute__((address_space(1))) void*)
                    (X + (size_t)(m0 + r0 + srow) * K + k0 + scol),
                (__attribute__((address_space(3))) void*)(As + r0 * 32),
                16, 0, 0);
            __builtin_amdgcn_global_load_lds(
                (const __attribute__((address_space(1))) void*)
                    (W + (size_t)(n0 + r0 + srow) * K + k0 + scol),
                (__attribute__((address_space(3))) void*)(Bs + r0 * 32),
                16, 0, 0);
        }
        __syncthreads();   // vmcnt drain: staged data visible

        bf16x8 af[4], bfr[4];
        #pragma unroll
        for (int i = 0; i < 4; ++i)
            af[i] = *(const bf16x8*)(As + (wm + i * 16 + fr) * 32 + fk);
        #pragma unroll
        for (int j = 0; j < 4; ++j)
            bfr[j] = *(const bf16x8*)(Bs + (wn + j * 16 + fr) * 32 + fk);
        #pragma unroll
        for (int i = 0; i < 4; ++i)
            #pragma unroll
            for (int j = 0; j < 4; ++j)
                acc[i][j] = __builtin_amdgcn_mfma_f32_16x16x32_bf16(
                    af[i], bfr[j], acc[i][j], 0, 0, 0);
    }

    // epilogue: C/D layout col=lane&15, row=(lane>>4)*4+reg
    const int col_l = lane & 15, quad = lane >> 4;
    #pragma unroll
    for (int j = 0; j < 4; ++j) {
        const int gcol = n0 + wn + j * 16 + col_l;
        const float bb = bias[gcol];
        #pragma unroll
        for (int i = 0; i < 4; ++i) {
            #pragma unroll
            for (int r = 0; r < 4; ++r) {
                const int grow = m0 + wm + i * 16 + quad * 4 + r;
                float v = acc[i][j][r] + bb;
                if (DO_PHI) v = phi_f(v);
                if (OUT_BF16)
                    ((__bf16*)Yv)[(size_t)grow * N + gcol] = (__bf16)v;
                else
                    ((float*)Yv)[(size_t)grow * N + gcol] = v;
            }
        }
    }
}

// ---------------------------------------------------------------------------
// Per (b,h,split): partial KV[d][e] = sum_n K[n,d]*V[n,e], partial Z[d].
// MFMA over LDS-transposed tiles Kt/Vt[64][36] (stride 36: b64-aligned frag
// reads, 4-way store conflicts max). Each thread stages a token-pair so
// transposed stores are packed bf16x2 dwords. No atomics: partials streamed
// to P[split], reduced by reduce_partials.
// ---------------------------------------------------------------------------
__global__ __launch_bounds__(256) void kv_z_kernel(
    const __bf16* __restrict__ Kb, const __bf16* __restrict__ Vb,
    float* __restrict__ P)
{
    __shared__ __attribute__((aligned(16))) __bf16 Kt[64 * 36]; // [d][tok]
    __shared__ __attribute__((aligned(16))) __bf16 Vt[64 * 36]; // [e][tok]
    __shared__ float zs[64];
    const int tid = threadIdx.x, wave = tid >> 6, lane = tid & 63;
    const int bh = blockIdx.x, b = bh >> 4, h = bh & 15;
    const int split = blockIdx.y;
    const int n0 = split * (SEQ / NSPLIT);
    const int dg = (tid & 15) * 4;     // 4 consecutive dims per thread
    const int u2 = (tid >> 4) * 2;     // token pair (0,2,..,30)
    const int fr = lane & 15, fk = (lane >> 4) * 8;
    const __bf16* Kp = Kb + ((size_t)b * SEQ + n0) * DIMC + h * HD;
    const __bf16* Vp = Vb + ((size_t)b * SEQ + n0) * DIMC + h * HD;

    if (tid < 64) zs[tid] = 0.0f;
    f32x4 acc[4] = {};                 // d-group wave*16, e-groups j=0..3
    float zp[4] = {};

    for (int c = 0; c < SEQ / NSPLIT; c += 32) {
        bf16x4 ka = *(const bf16x4*)(Kp + (size_t)(c + u2) * DIMC + dg);
        bf16x4 kb = *(const bf16x4*)(Kp + (size_t)(c + u2 + 1) * DIMC + dg);
        bf16x4 va = *(const bf16x4*)(Vp + (size_t)(c + u2) * DIMC + dg);
        bf16x4 vb = *(const bf16x4*)(Vp + (size_t)(c + u2 + 1) * DIMC + dg);
        __syncthreads();   // previous chunk's frag reads complete
        #pragma unroll
        for (int q = 0; q < 4; ++q) {
            zp[q] += (float)ka[q] + (float)kb[q];
            *(bf16x2*)(Kt + (dg + q) * 36 + u2) = bf16x2{ka[q], kb[q]};
            *(bf16x2*)(Vt + (dg + q) * 36 + u2) = bf16x2{va[q], vb[q]};
        }
        __syncthreads();

        // A-frag: Kt row d = wave*16+fr, toks fk..fk+7 (two b64 reads)
        const __bf16* ar = Kt + (wave * 16 + fr) * 36 + fk;
        bf16x4 alo = *(const bf16x4*)ar, ahi = *(const bf16x4*)(ar + 4);
        bf16x8 af = {alo[0],alo[1],alo[2],alo[3],ahi[0],ahi[1],ahi[2],ahi[3]};
        #pragma unroll
        for (int j = 0; j < 4; ++j) {
            const __bf16* br = Vt + (j * 16 + fr) * 36 + fk;
            bf16x4 blo = *(const bf16x4*)br, bhi = *(const bf16x4*)(br + 4);
            bf16x8 bf = {blo[0],blo[1],blo[2],blo[3],bhi[0],bhi[1],bhi[2],bhi[3]};
            acc[j] = __builtin_amdgcn_mfma_f32_16x16x32_bf16(af, bf, acc[j], 0, 0, 0);
        }
    }

    #pragma unroll
    for (int q = 0; q < 4; ++q) atomicAdd(&zs[dg + q], zp[q]);
    __syncthreads();

    float* KVp = P + (size_t)split * PELEMS + bh * 4096;
    const int col_l = lane & 15, quad = lane >> 4;
    #pragma unroll
    for (int j = 0; j < 4; ++j)
        #pragma unroll
        for (int r = 0; r < 4; ++r)
            KVp[(wave * 16 + quad * 4 + r) * 64 + j * 16 + col_l] = acc[j][r];
    if (tid < 64)
        P[(size_t)split * PELEMS + 64 * 64 * 64 + bh * 64 + tid] = zs[tid];
}

// sum NSPLIT partials -> final KV+Z (contiguous PELEMS floats)
__global__ __launch_bounds__(256) void reduce_partials(
    const float* __restrict__ P, float* __restrict__ F)
{
    const int i = blockIdx.x * 256 + threadIdx.x;
    if (i < PELEMS) {
        float s = 0.0f;
        #pragma unroll
        for (int sp = 0; sp < NSPLIT; ++sp) s += P[(size_t)sp * PELEMS + i];
        F[i] = s;
    }
}

// ---------------------------------------------------------------------------
// Per (b,h, 32-token chunk): out[n,e] = (sum_d Q[n,d]*KV[d,e]) / (Q[n]·Z + eps)
// ---------------------------------------------------------------------------
__global__ __launch_bounds__(256) void attn_apply(
    const __bf16* __restrict__ Qb, const float* __restrict__ KV,
    const float* __restrict__ Z, __bf16* __restrict__ Ab)
{
    __shared__ __align__(16) float KVs[64][64];
    __shared__ __align__(16) float Qs[32][64];
    __shared__ float Zs[64];
    __shared__ float rnorm[32];
    const int tid = threadIdx.x;
    const int bh = blockIdx.y;
    const int b = bh >> 4, h = bh & 15;
    const int n0 = blockIdx.x * 32;

    const float* KVp = KV + (size_t)bh * HD * HD;
    #pragma unroll
    for (int r = 0; r < 4; ++r) {
        const int idx = (r * 256 + tid) * 4;
        *(float4*)&((float*)KVs)[idx] = *(const float4*)(KVp + idx);
    }
    const __bf16* Qp = Qb + ((size_t)(b * SEQ + n0)) * DIMC + h * HD;
    {
        const int tok = tid >> 3, col = (tid & 7) * 8;
        bf16x8 q8 = *(const bf16x8*)(Qp + (size_t)tok * DIMC + col);
        #pragma unroll
        for (int q = 0; q < 8; ++q) Qs[tok][col + q] = (float)q8[q];
    }
    if (tid < 64) Zs[tid] = Z[bh * HD + tid];
    __syncthreads();

    if (tid < 32) {
        float s = 0.0f;
        #pragma unroll
        for (int d = 0; d < 64; ++d) s += Qs[tid][d] * Zs[d];
        rnorm[tid] = 1.0f / (s + EPS);
    }
    __syncthreads();

    const int trow = tid >> 3;
    const int e0 = (tid & 7) * 8;
    float out[8] = {};
    #pragma unroll
    for (int d = 0; d < 64; ++d) {
        const float q = Qs[trow][d];
        #pragma unroll
        for (int j = 0; j < 8; ++j) out[j] = fmaf(q, KVs[d][e0 + j], out[j]);
    }
    const float rn = rnorm[trow];
    __bf16* Op = Ab + ((size_t)(b * SEQ + n0 + trow)) * DIMC + h * HD + e0;
    bf16x8 o;
    #pragma unroll
    for (int j = 0; j < 8; ++j) o[j] = (__bf16)(out[j] * rn);
    *(bf16x8*)Op = o;
}

extern "C" void kernel_launch(void* const* d_in, const int* in_sizes, int n_in,
                              void* d_out, int out_size, void* d_ws, size_t ws_size,
                              hipStream_t stream) {
    const float* x  = (const float*)d_in[0];
    const float* Wq = (const float*)d_in[1];
    const float* bq = (const float*)d_in[2];
    const float* Wk = (const float*)d_in[3];
    const float* bk = (const float*)d_in[4];
    const float* Wv = (const float*)d_in[5];
    const float* bv = (const float*)d_in[6];
    const float* Wo = (const float*)d_in[7];
    const float* bo = (const float*)d_in[8];
    float* out = (float*)d_out;

    const size_t big = (size_t)MTOT * DIMC;     // 16,777,216 elems
    const size_t wsz = (size_t)DIMC * DIMC;     // 1,048,576 elems
    __bf16* wsp = (__bf16*)d_ws;
    __bf16* xb  = wsp;
    __bf16* Wqb = xb + big;
    __bf16* Wkb = Wqb + wsz;
    __bf16* Wvb = Wkb + wsz;
    __bf16* Wob = Wvb + wsz;
    __bf16* Qb  = Wob + wsz;
    __bf16* Kb  = Qb + big;
    __bf16* Vb  = Kb + big;
    __bf16* Ab  = xb;                            // alias: x dead after V gemm
    float*  P   = (float*)(Vb + big);            // NSPLIT * PELEMS partials
    float*  F   = P + (size_t)NSPLIT * PELEMS;   // final KV (262144) + Z (4096)
    float*  KV  = F;
    float*  Z   = F + 64 * 64 * 64;
    // total ~152 MB

    cvt_bf16<<<dim3(big / 1024), 256, 0, stream>>>(x, xb, (int)big);
    cvt_bf16_w4<<<dim3(wsz / 1024, 4), 256, 0, stream>>>(
        Wq, Wk, Wv, Wo, Wqb, Wkb, Wvb, Wob, (int)wsz);

    dim3 gg(DIMC / 128, MTOT / 128);   // (8, 128)
    gemm_bf16<1, 1><<<gg, 256, 0, stream>>>(xb, Wqb, bq, Qb, DIMC, DIMC);
    gemm_bf16<1, 1><<<gg, 256, 0, stream>>>(xb, Wkb, bk, Kb, DIMC, DIMC);
    gemm_bf16<1, 0><<<gg, 256, 0, stream>>>(xb, Wvb, bv, Vb, DIMC, DIMC);

    kv_z_kernel<<<dim3(BATCH * NH, NSPLIT), 256, 0, stream>>>(Kb, Vb, P);
    reduce_partials<<<dim3((PELEMS + 255) / 256), 256, 0, stream>>>(P, F);
    attn_apply<<<dim3(SEQ / 32, BATCH * NH), 256, 0, stream>>>(Qb, KV, Z, Ab);

    gemm_bf16<0, 0><<<gg, 256, 0, stream>>>(Ab, Wob, bo, out, DIMC, DIMC);
}

// Round 4
// 388.288 us; speedup vs baseline: 1.3799x; 1.1932x over previous
//
#include <hip/hip_runtime.h>
#include <math.h>

#define DIMC 1024
#define SEQ 4096
#define BATCH 4
#define NH 16
#define HD 64
#define MTOT (BATCH * SEQ)      // 16384 rows
#define NSPLIT 8
#define PELEMS (64 * 64 * 64 + 64 * 64)   // KV partial + Z partial per split
#define EPS 1e-6f

typedef __bf16 bf16x8 __attribute__((ext_vector_type(8)));
typedef __bf16 bf16x4 __attribute__((ext_vector_type(4)));
typedef __bf16 bf16x2 __attribute__((ext_vector_type(2)));
typedef float  f32x4  __attribute__((ext_vector_type(4)));

__device__ __forceinline__ float phi_f(float x) {
    return x > 0.0f ? x + 1.0f : __expf(x);   // elu(x)+1
}

// ---------------------------------------------------------------------------
// One-shot fp32->bf16 conversion of x + all 4 weight matrices.
// ---------------------------------------------------------------------------
__global__ __launch_bounds__(256) void cvt_all(
    const float* __restrict__ x,
    const float* __restrict__ Wq, const float* __restrict__ Wk,
    const float* __restrict__ Wv, const float* __restrict__ Wo,
    __bf16* __restrict__ xb,
    __bf16* __restrict__ Wqb, __bf16* __restrict__ Wkb,
    __bf16* __restrict__ Wvb, __bf16* __restrict__ Wob)
{
    const size_t big = (size_t)MTOT * DIMC;
    const size_t wsz = (size_t)DIMC * DIMC;
    size_t i = ((size_t)blockIdx.x * 256 + threadIdx.x) * 4;
    const float* src; __bf16* dst; size_t off;
    if (i < big) { src = x; dst = xb; off = i; }
    else {
        size_t j = i - big;
        int w = (int)(j >> 20);            // /wsz (2^20)
        off = j & (wsz - 1);
        switch (w) {
            case 0: src = Wq; dst = Wqb; break;
            case 1: src = Wk; dst = Wkb; break;
            case 2: src = Wv; dst = Wvb; break;
            default: src = Wo; dst = Wob; break;
        }
    }
    float4 v = *(const float4*)(src + off);
    bf16x4 o = { (__bf16)v.x, (__bf16)v.y, (__bf16)v.z, (__bf16)v.w };
    *(bf16x4*)(dst + off) = o;
}

// ---------------------------------------------------------------------------
// Shared 128x128 MFMA GEMM tile body (m97 structure).
// Y[m0..+128, n0..+128] = X[m0..,:] @ W[n0..,:]^T + bias, K=N=DIMC.
// ---------------------------------------------------------------------------
template<int OUT_BF16>
__device__ __forceinline__ void gemm_tile(
    const __bf16* __restrict__ X, const __bf16* __restrict__ W,
    const float* __restrict__ bias, void* __restrict__ Yv,
    int m0, int n0, int do_phi)
{
    __shared__ __attribute__((aligned(16))) __bf16 As[128 * 32]; // [m][k]
    __shared__ __attribute__((aligned(16))) __bf16 Bs[128 * 32]; // [n][k]
    const int tid = threadIdx.x;
    const int wave = tid >> 6, lane = tid & 63;
    const int wm = (wave >> 1) * 64, wn = (wave & 1) * 64;
    const int srow = lane >> 2, scol = (lane & 3) * 8;  // staging lane map
    const int fr = lane & 15, fk = (lane >> 4) * 8;     // fragment lane map

    f32x4 acc[4][4] = {};

    for (int k0 = 0; k0 < DIMC; k0 += 32) {
        __syncthreads();   // previous tile's ds_reads complete
        #pragma unroll
        for (int g = 0; g < 2; ++g) {
            const int r0 = wave * 16 + g * 64;   // 16-row group per call
            __builtin_amdgcn_global_load_lds(
                (const __attribute__((address_space(1))) void*)
                    (X + (size_t)(m0 + r0 + srow) * DIMC + k0 + scol),
                (__attribute__((address_space(3))) void*)(As + r0 * 32),
                16, 0, 0);
            __builtin_amdgcn_global_load_lds(
                (const __attribute__((address_space(1))) void*)
                    (W + (size_t)(n0 + r0 + srow) * DIMC + k0 + scol),
                (__attribute__((address_space(3))) void*)(Bs + r0 * 32),
                16, 0, 0);
        }
        __syncthreads();   // vmcnt drain: staged data visible

        bf16x8 af[4], bfr[4];
        #pragma unroll
        for (int i = 0; i < 4; ++i)
            af[i] = *(const bf16x8*)(As + (wm + i * 16 + fr) * 32 + fk);
        #pragma unroll
        for (int j = 0; j < 4; ++j)
            bfr[j] = *(const bf16x8*)(Bs + (wn + j * 16 + fr) * 32 + fk);
        #pragma unroll
        for (int i = 0; i < 4; ++i)
            #pragma unroll
            for (int j = 0; j < 4; ++j)
                acc[i][j] = __builtin_amdgcn_mfma_f32_16x16x32_bf16(
                    af[i], bfr[j], acc[i][j], 0, 0, 0);
    }

    // epilogue: C/D layout col=lane&15, row=(lane>>4)*4+reg
    const int col_l = lane & 15, quad = lane >> 4;
    #pragma unroll
    for (int j = 0; j < 4; ++j) {
        const int gcol = n0 + wn + j * 16 + col_l;
        const float bb = bias[gcol];
        #pragma unroll
        for (int i = 0; i < 4; ++i) {
            #pragma unroll
            for (int r = 0; r < 4; ++r) {
                const int grow = m0 + wm + i * 16 + quad * 4 + r;
                float v = acc[i][j][r] + bb;
                if (do_phi) v = phi_f(v);
                if (OUT_BF16)
                    ((__bf16*)Yv)[(size_t)grow * DIMC + gcol] = (__bf16)v;
                else
                    ((float*)Yv)[(size_t)grow * DIMC + gcol] = v;
            }
        }
    }
}

// ---------------------------------------------------------------------------
// Fused Q/K/V projection. 3072 blocks, XCD-swizzled: blocks sharing an
// X-panel (24 = 3 matrices x 8 n-blocks) land on ONE XCD's L2.
// Round-robin assumption: xcd = blockIdx % 8 (speed-only heuristic).
// ---------------------------------------------------------------------------
__global__ __launch_bounds__(256, 3) void gemm_qkv(
    const __bf16* __restrict__ X,
    const __bf16* __restrict__ Wq, const __bf16* __restrict__ Wk,
    const __bf16* __restrict__ Wv,
    const float* __restrict__ bq, const float* __restrict__ bk,
    const float* __restrict__ bv,
    __bf16* __restrict__ Q, __bf16* __restrict__ K, __bf16* __restrict__ V)
{
    const int l = blockIdx.x;
    const int xcd = l & 7, s = l >> 3;          // s in [0,384)
    const int m_idx = xcd * 16 + (s / 24);      // 16 m-panels per XCD
    const int inner = s % 24;
    const int mat = inner >> 3, nb = inner & 7;
    const __bf16* W = (mat == 0) ? Wq : (mat == 1) ? Wk : Wv;
    const float* bias = (mat == 0) ? bq : (mat == 1) ? bk : bv;
    __bf16* Y = (mat == 0) ? Q : (mat == 1) ? K : V;
    gemm_tile<1>(X, W, bias, Y, m_idx * 128, nb * 128, mat != 2);
}

// ---------------------------------------------------------------------------
// Output projection: out = A @ Wo^T + bo (fp32 out). XCD-swizzled:
// 8 n-blocks sharing an A-panel stay on one XCD.
// ---------------------------------------------------------------------------
__global__ __launch_bounds__(256, 3) void gemm_out(
    const __bf16* __restrict__ A, const __bf16* __restrict__ Wo,
    const float* __restrict__ bo, float* __restrict__ out)
{
    const int l = blockIdx.x;
    const int xcd = l & 7, s = l >> 3;          // s in [0,128)
    const int m_idx = xcd * 16 + (s >> 3);
    const int nb = s & 7;
    gemm_tile<0>(A, Wo, bo, out, m_idx * 128, nb * 128, 0);
}

// ---------------------------------------------------------------------------
// Per (b,h,split): partial KV[d][e] = sum_n K[n,d]*V[n,e], partial Z[d].
// MFMA over LDS-transposed tiles; partials streamed, no global atomics.
// ---------------------------------------------------------------------------
__global__ __launch_bounds__(256) void kv_z_kernel(
    const __bf16* __restrict__ Kb, const __bf16* __restrict__ Vb,
    float* __restrict__ P)
{
    __shared__ __attribute__((aligned(16))) __bf16 Kt[64 * 36]; // [d][tok]
    __shared__ __attribute__((aligned(16))) __bf16 Vt[64 * 36]; // [e][tok]
    __shared__ float zs[64];
    const int tid = threadIdx.x, wave = tid >> 6, lane = tid & 63;
    const int bh = blockIdx.x, b = bh >> 4, h = bh & 15;
    const int split = blockIdx.y;
    const int n0 = split * (SEQ / NSPLIT);
    const int dg = (tid & 15) * 4;     // 4 consecutive dims per thread
    const int u2 = (tid >> 4) * 2;     // token pair
    const int fr = lane & 15, fk = (lane >> 4) * 8;
    const __bf16* Kp = Kb + ((size_t)b * SEQ + n0) * DIMC + h * HD;
    const __bf16* Vp = Vb + ((size_t)b * SEQ + n0) * DIMC + h * HD;

    if (tid < 64) zs[tid] = 0.0f;
    f32x4 acc[4] = {};
    float zp[4] = {};

    for (int c = 0; c < SEQ / NSPLIT; c += 32) {
        bf16x4 ka = *(const bf16x4*)(Kp + (size_t)(c + u2) * DIMC + dg);
        bf16x4 kb = *(const bf16x4*)(Kp + (size_t)(c + u2 + 1) * DIMC + dg);
        bf16x4 va = *(const bf16x4*)(Vp + (size_t)(c + u2) * DIMC + dg);
        bf16x4 vb = *(const bf16x4*)(Vp + (size_t)(c + u2 + 1) * DIMC + dg);
        __syncthreads();
        #pragma unroll
        for (int q = 0; q < 4; ++q) {
            zp[q] += (float)ka[q] + (float)kb[q];
            *(bf16x2*)(Kt + (dg + q) * 36 + u2) = bf16x2{ka[q], kb[q]};
            *(bf16x2*)(Vt + (dg + q) * 36 + u2) = bf16x2{va[q], vb[q]};
        }
        __syncthreads();

        const __bf16* ar = Kt + (wave * 16 + fr) * 36 + fk;
        bf16x4 alo = *(const bf16x4*)ar, ahi = *(const bf16x4*)(ar + 4);
        bf16x8 af = {alo[0],alo[1],alo[2],alo[3],ahi[0],ahi[1],ahi[2],ahi[3]};
        #pragma unroll
        for (int j = 0; j < 4; ++j) {
            const __bf16* br = Vt + (j * 16 + fr) * 36 + fk;
            bf16x4 blo = *(const bf16x4*)br, bhi = *(const bf16x4*)(br + 4);
            bf16x8 bf = {blo[0],blo[1],blo[2],blo[3],bhi[0],bhi[1],bhi[2],bhi[3]};
            acc[j] = __builtin_amdgcn_mfma_f32_16x16x32_bf16(af, bf, acc[j], 0, 0, 0);
        }
    }

    #pragma unroll
    for (int q = 0; q < 4; ++q) atomicAdd(&zs[dg + q], zp[q]);
    __syncthreads();

    float* KVp = P + (size_t)split * PELEMS + bh * 4096;
    const int col_l = lane & 15, quad = lane >> 4;
    #pragma unroll
    for (int j = 0; j < 4; ++j)
        #pragma unroll
        for (int r = 0; r < 4; ++r)
            KVp[(wave * 16 + quad * 4 + r) * 64 + j * 16 + col_l] = acc[j][r];
    if (tid < 64)
        P[(size_t)split * PELEMS + 64 * 64 * 64 + bh * 64 + tid] = zs[tid];
}

// sum NSPLIT partials -> final KV+Z (contiguous PELEMS floats)
__global__ __launch_bounds__(256) void reduce_partials(
    const float* __restrict__ P, float* __restrict__ F)
{
    const int i = blockIdx.x * 256 + threadIdx.x;
    if (i < PELEMS) {
        float s = 0.0f;
        #pragma unroll
        for (int sp = 0; sp < NSPLIT; ++sp) s += P[(size_t)sp * PELEMS + i];
        F[i] = s;
    }
}

// ---------------------------------------------------------------------------
// Per (b,h, 32-token chunk): out[n,e] = (sum_d Q[n,d]*KV[d,e]) / (Q[n]·Z + eps)
// ---------------------------------------------------------------------------
__global__ __launch_bounds__(256) void attn_apply(
    const __bf16* __restrict__ Qb, const float* __restrict__ KV,
    const float* __restrict__ Z, __bf16* __restrict__ Ab)
{
    __shared__ __align__(16) float KVs[64][64];
    __shared__ __align__(16) float Qs[32][64];
    __shared__ float Zs[64];
    __shared__ float rnorm[32];
    const int tid = threadIdx.x;
    const int bh = blockIdx.y;
    const int b = bh >> 4, h = bh & 15;
    const int n0 = blockIdx.x * 32;

    const float* KVp = KV + (size_t)bh * HD * HD;
    #pragma unroll
    for (int r = 0; r < 4; ++r) {
        const int idx = (r * 256 + tid) * 4;
        *(float4*)&((float*)KVs)[idx] = *(const float4*)(KVp + idx);
    }
    const __bf16* Qp = Qb + ((size_t)(b * SEQ + n0)) * DIMC + h * HD;
    {
        const int tok = tid >> 3, col = (tid & 7) * 8;
        bf16x8 q8 = *(const bf16x8*)(Qp + (size_t)tok * DIMC + col);
        #pragma unroll
        for (int q = 0; q < 8; ++q) Qs[tok][col + q] = (float)q8[q];
    }
    if (tid < 64) Zs[tid] = Z[bh * HD + tid];
    __syncthreads();

    if (tid < 32) {
        float s = 0.0f;
        #pragma unroll
        for (int d = 0; d < 64; ++d) s += Qs[tid][d] * Zs[d];
        rnorm[tid] = 1.0f / (s + EPS);
    }
    __syncthreads();

    const int trow = tid >> 3;
    const int e0 = (tid & 7) * 8;
    float out[8] = {};
    #pragma unroll
    for (int d = 0; d < 64; ++d) {
        const float q = Qs[trow][d];
        #pragma unroll
        for (int j = 0; j < 8; ++j) out[j] = fmaf(q, KVs[d][e0 + j], out[j]);
    }
    const float rn = rnorm[trow];
    __bf16* Op = Ab + ((size_t)(b * SEQ + n0 + trow)) * DIMC + h * HD + e0;
    bf16x8 o;
    #pragma unroll
    for (int j = 0; j < 8; ++j) o[j] = (__bf16)(out[j] * rn);
    *(bf16x8*)Op = o;
}

extern "C" void kernel_launch(void* const* d_in, const int* in_sizes, int n_in,
                              void* d_out, int out_size, void* d_ws, size_t ws_size,
                              hipStream_t stream) {
    const float* x  = (const float*)d_in[0];
    const float* Wq = (const float*)d_in[1];
    const float* bq = (const float*)d_in[2];
    const float* Wk = (const float*)d_in[3];
    const float* bk = (const float*)d_in[4];
    const float* Wv = (const float*)d_in[5];
    const float* bv = (const float*)d_in[6];
    const float* Wo = (const float*)d_in[7];
    const float* bo = (const float*)d_in[8];
    float* out = (float*)d_out;

    const size_t big = (size_t)MTOT * DIMC;     // 16,777,216 elems
    const size_t wsz = (size_t)DIMC * DIMC;     // 1,048,576 elems
    __bf16* wsp = (__bf16*)d_ws;
    __bf16* xb  = wsp;
    __bf16* Wqb = xb + big;
    __bf16* Wkb = Wqb + wsz;
    __bf16* Wvb = Wkb + wsz;
    __bf16* Wob = Wvb + wsz;
    __bf16* Qb  = Wob + wsz;
    __bf16* Kb  = Qb + big;
    __bf16* Vb  = Kb + big;
    __bf16* Ab  = xb;                            // alias: x dead after QKV
    float*  P   = (float*)(Vb + big);            // NSPLIT * PELEMS partials
    float*  F   = P + (size_t)NSPLIT * PELEMS;
    float*  KV  = F;
    float*  Z   = F + 64 * 64 * 64;

    const size_t ntot = big + 4 * wsz;           // 20,971,520 elems
    cvt_all<<<dim3((int)(ntot / 1024)), 256, 0, stream>>>(
        x, Wq, Wk, Wv, Wo, xb, Wqb, Wkb, Wvb, Wob);

    gemm_qkv<<<dim3(3072), 256, 0, stream>>>(
        xb, Wqb, Wkb, Wvb, bq, bk, bv, Qb, Kb, Vb);

    kv_z_kernel<<<dim3(BATCH * NH, NSPLIT), 256, 0, stream>>>(Kb, Vb, P);
    reduce_partials<<<dim3((PELEMS + 255) / 256), 256, 0, stream>>>(P, F);
    attn_apply<<<dim3(SEQ / 32, BATCH * NH), 256, 0, stream>>>(Qb, KV, Z, Ab);

    gemm_out<<<dim3(1024), 256, 0, stream>>>(Ab, Wob, bo, out);
}